// Round 13
// baseline (161.652 us; speedup 1.0000x reference)
//
#include <hip/hip_runtime.h>
#include <stdint.h>

#define DIMD 512
#define BATCH 512
#define KSAMP 10
#define NCLS 8192
#define TREJ 32

typedef float f32x4 __attribute__((ext_vector_type(4)));
typedef long l2 __attribute__((ext_vector_type(2)));

// ---------------- RNG (counter-based, deterministic) ----------------
__device__ inline uint64_t sm64(uint64_t x) {
  x += 0x9E3779B97F4A7C15ull;
  x = (x ^ (x >> 30)) * 0xBF58476D1CE4E5B9ull;
  x = (x ^ (x >> 27)) * 0x94D049BB133111EBull;
  return x ^ (x >> 31);
}
__device__ inline float u01(uint32_t u) {
  return ((float)u + 0.5f) * 2.3283064365386963e-10f;
}
__device__ inline float normal_from(uint64_t r) {
  float u1 = u01((uint32_t)(r >> 32));
  float u2 = u01((uint32_t)r);
  return sqrtf(-2.0f * __logf(u1)) * __cosf(6.28318530718f * u2);
}
__device__ inline float gamma255(uint64_t& ctr) {
  const float dg = 255.1666667f;
  const float cg = 0.02086730f;
  for (int i = 0; i < 16; i++) {
    uint64_t r = sm64(ctr++);
    float x = normal_from(r);
    float t = fmaf(cg, x, 1.0f);
    if (t <= 0.0f) continue;
    float v3 = t * t * t;
    uint64_t r2 = sm64(ctr++);
    float u3 = u01((uint32_t)(r2 >> 32));
    if (__logf(u3) < 0.5f * x * x + dg * (1.0f - v3 + __logf(v3))) return dg * v3;
  }
  return dg;
}
__device__ inline float wave_sum(float v) {
  #pragma unroll
  for (int o = 32; o > 0; o >>= 1) v += __shfl_down(v, o, 64);
  return __shfl(v, 0, 64);
}
__device__ inline float vmf_logc(float k) {
  float k2 = k * k;
  float sm = sqrtf(65280.25f + k2);
  float sp = sqrtf(65792.25f + k2);
  return 127.75f * (logf(255.5f + sm) + logf(255.5f + sp)) - 0.5f * (sm + sp);
}
// pack 8 floats (scaled) -> 8 fp8 e4m3 bytes (2 dwords)
__device__ inline int2 pack_fp8x8(const float* v, float s) {
  int lo = 0, hi = 0;
  lo = __builtin_amdgcn_cvt_pk_fp8_f32(v[0] * s, v[1] * s, lo, false);
  lo = __builtin_amdgcn_cvt_pk_fp8_f32(v[2] * s, v[3] * s, lo, true);
  hi = __builtin_amdgcn_cvt_pk_fp8_f32(v[4] * s, v[5] * s, hi, false);
  hi = __builtin_amdgcn_cvt_pk_fp8_f32(v[6] * s, v[7] * s, hi, true);
  return make_int2(lo, hi);
}
// packed-row byte offset for lane l holding k in [8l, 8l+8) (verified map)
__device__ inline int pk_off(int l) {
  return ((l >> 3) << 6) + ((l & 3) << 4) + (((l & 7) < 4) ? 0 : 8);
}
__device__ inline void async16(const unsigned char* g, unsigned char* l) {
  __builtin_amdgcn_global_load_lds(
      (const __attribute__((address_space(1))) unsigned int*)g,
      (__attribute__((address_space(3))) unsigned int*)l, 16, 0, 0);
}

// ---------- fused prep (blocks 0..2047, one WAVE per class) + sample ----------
__global__ __launch_bounds__(256) void prep_sample(const float* __restrict__ weight,
                                                   const float* __restrict__ params,
                                                   const float* __restrict__ lscale,
                                                   unsigned char* __restrict__ muW8,
                                                   float4* __restrict__ cparams,
                                                   float* __restrict__ rowsum,
                                                   float4* __restrict__ out4,
                                                   unsigned char* __restrict__ Sb8) {
  int blk = blockIdx.x, tid = threadIdx.x;
  int wave = tid >> 6, lane = tid & 63;
  if (blk < 2048) {
    out4[(size_t)blk * 512 + tid]       = make_float4(0.f, 0.f, 0.f, 0.f);
    out4[(size_t)blk * 512 + 256 + tid] = make_float4(0.f, 0.f, 0.f, 0.f);
    if (blk < 20) rowsum[blk * 256 + tid] = 0.0f;   // 20*256 = 5120

    int c = blk * 4 + wave;                 // one wave per class
    const float* wr = weight + (size_t)c * (DIMD + 2) + 1;
    float v[8];
    float n2 = 0.0f;
    #pragma unroll
    for (int j = 0; j < 8; j++) { v[j] = wr[lane * 8 + j]; n2 += v[j] * v[j]; }
    n2 = wave_sum(n2);
    float inv = rsqrtf(n2) * 16.0f;         // x16: dodge e4m3 subnormals
    int2 pk = pack_fp8x8(v, inv);
    *(int2*)(muW8 + (size_t)c * 512 + pk_off(lane)) = pk;

    float hik = wr[DIMD];                   // col 513
    float kw = expf(-hik);
    float k1 = expf(lscale[0]);
    float lcw = vmf_logc(kw);
    float A2 = fmaf(k1, k1, kw * kw);
    float B2 = 2.0f * k1 * kw;
    const float X0 = 0.9238795f, X1 = 0.3826834f;
    int l3 = lane & 3;
    float Xj = (l3 == 0) ? X0 : (l3 == 1) ? X1 : (l3 == 2) ? -X1 : -X0;
    float gj = lcw - vmf_logc(sqrtf(fmaf(B2, Xj, A2)));
    float g0 = __shfl(gj, 0, 64), g1 = __shfl(gj, 1, 64);
    float g2 = __shfl(gj, 2, 64), g3 = __shfl(gj, 3, 64);
    if (lane == 0) {
      float b0 = 0.25f * (g0 + g1 + g2 + g3);
      float b1 = 0.5f * (X0 * (g0 - g3) + X1 * (g1 - g2));
      float b2 = 0.5f * 0.7071068f * ((g0 + g3) - (g1 + g2));
      float b3 = 0.5f * (X1 * (g0 - g3) - X0 * (g1 - g2));
      const float L2E = 1.4426950409f;
      const float S1 = 1.0f / 256.0f;       // acc = 256*cos -> rescale poly
      cparams[c] = make_float4((b0 - b2) * L2E, (b1 - 3.0f * b3) * L2E * S1,
                               (2.0f * b2) * L2E * S1 * S1,
                               (4.0f * b3) * L2E * S1 * S1 * S1);
    }
  } else {
    // sample: 1 wave per row; lane l owns k in [8l, 8l+8) (contiguous).
    int row = (blk - 2048) * 4 + wave;      // b*KSAMP + k
    int b = row / KSAMP;
    const float* pr = params + (size_t)b * (DIMD + 2) + 1;

    float mu[8];
    float n2 = 0.0f;
    #pragma unroll
    for (int j = 0; j < 8; j++) { mu[j] = pr[lane * 8 + j]; n2 += mu[j] * mu[j]; }
    n2 = wave_sum(n2);
    float invn = rsqrtf(n2);
    #pragma unroll
    for (int j = 0; j < 8; j++) mu[j] *= invn;

    float kap = __expf(-pr[DIMD]);
    float bb = (-2.0f * kap + sqrtf(fmaf(4.0f * kap, kap, 511.0f * 511.0f))) / 511.0f;
    float x0 = (1.0f - bb) / (1.0f + bb);
    float cc = kap * x0 + 511.0f * __logf(1.0f - x0 * x0);

    uint64_t ctr = (((uint64_t)(row + 1)) << 32) | ((uint64_t)lane << 8);
    float g1 = gamma255(ctr);
    float g2 = gamma255(ctr);
    float z = g1 / (g1 + g2);
    float wt = (1.0f - (1.0f + bb) * z) / (1.0f - (1.0f - bb) * z);
    uint64_t r = sm64(ctr++);
    float u = u01((uint32_t)(r >> 32));
    float lhs = kap * wt + 511.0f * __logf(1.0f - x0 * wt) - cc;
    bool acc = (lane < TREJ) && (lhs >= __logf(fmaxf(u, 1e-10f)));
    uint64_t mask = __ballot(acc);
    int sel = mask ? (__ffsll((unsigned long long)mask) - 1) : 0;
    float w = __shfl(wt, sel, 64);

    uint64_t cbase = (((uint64_t)(row + 1)) << 32) | 0x40000000ull;
    float v[8];
    #pragma unroll
    for (int j = 0; j < 8; j++) v[j] = normal_from(sm64(cbase + (uint64_t)(lane * 8 + j)));
    float d = 0.0f;
    #pragma unroll
    for (int j = 0; j < 8; j++) d += v[j] * mu[j];
    d = wave_sum(d);
    float t2 = 0.0f;
    #pragma unroll
    for (int j = 0; j < 8; j++) { v[j] -= d * mu[j]; t2 += v[j] * v[j]; }
    t2 = wave_sum(t2);
    float ivt = rsqrtf(t2);
    float st = sqrtf(fmaxf(0.0f, 1.0f - w * w)) * ivt;
    float sv[8];
    float s2 = 0.0f;
    #pragma unroll
    for (int j = 0; j < 8; j++) { sv[j] = fmaf(st, v[j], w * mu[j]); s2 += sv[j] * sv[j]; }
    s2 = wave_sum(s2);
    float is = rsqrtf(s2) * 16.0f;
    int2 pk = pack_fp8x8(sv, is);
    *(int2*)(Sb8 + (size_t)row * 512 + pk_off(lane)) = pk;
  }
}

// MFMA GEMM: fp8 e4m3, 128x128 tile, BK=64, 8 iterations. R11's verified
// global_load_lds ping-pong (single barrier/iter) with acc[4][4] = 64 AGPR
// so launch_bounds(256,3) gives 3 waves/SIMD (vs R11's 2) -> more co-resident
// waves to hide the barrier drain + more loads in flight chip-wide.
__global__ __launch_bounds__(256, 3) void gemm_lse(const unsigned char* __restrict__ Sb8,
                                                   const unsigned char* __restrict__ Wb8,
                                                   const float4* __restrict__ cparams,
                                                   float* __restrict__ rowsum) {
  __shared__ __align__(16) unsigned char As[2][128 * 64];   // 2 x 8 KB
  __shared__ __align__(16) unsigned char Bs[2][128 * 64];   // 2 x 8 KB
  int tid = threadIdx.x;
  int lane = tid & 63, wave = tid >> 6;
  int wm = wave >> 1, wn = wave & 1;
  int tx = lane & 15, tz = lane >> 4;

  int id = blockIdx.x;                       // 64 col-tiles x 40 row-tiles = 2560
  int xcd = id & 7, lid = id >> 3;           // 320 blocks per XCD
  int c0 = (xcd * 8 + (lid & 7)) * 128;      // 8-coltile stripe per XCD (L2-resident W)
  int r0 = (lid >> 3) * 128;                 // sweep 40 row tiles

  int srow = (lane >> 2);                       // 0..15 within chunk
  int kg   = (lane & 3) ^ ((lane >> 3) & 3);    // verified swizzle
  int chA0 = wave * 2;                          // A: 8 chunks of 16 rows, 2/wave
  int chB0 = wave * 2;                          // B: 8 chunks, 2/wave

  f32x4 acc[4][4];
  #pragma unroll
  for (int i = 0; i < 4; i++)
    #pragma unroll
    for (int j = 0; j < 4; j++) acc[i][j] = (f32x4){0.f, 0.f, 0.f, 0.f};

  #pragma unroll
  for (int c = 0; c < 2; c++) {
    int ch = chA0 + c, rowi = ch * 16 + srow;
    async16(&Sb8[(size_t)(r0 + rowi) * 512 + kg * 16], &As[0][ch * 1024]);
    async16(&Wb8[(size_t)(c0 + rowi) * 512 + kg * 16], &Bs[0][ch * 1024]);
  }

  int p = 0;
  for (int kt = 0; kt < 512; kt += 64) {       // 8 iterations
    __syncthreads();   // publishes buf[p]
    if (kt + 64 < 512) {
      #pragma unroll
      for (int c = 0; c < 2; c++) {
        int ch = chA0 + c, rowi = ch * 16 + srow;
        async16(&Sb8[(size_t)(r0 + rowi) * 512 + kt + 64 + kg * 16], &As[p ^ 1][ch * 1024]);
        async16(&Wb8[(size_t)(c0 + rowi) * 512 + kt + 64 + kg * 16], &Bs[p ^ 1][ch * 1024]);
      }
    }
    l2 af[4], bf[4];
    int sA = tz ^ ((tx >> 1) & 3);
    #pragma unroll
    for (int mi = 0; mi < 4; mi++) {
      af[mi] = *(const l2*)&As[p][(wm * 64 + mi * 16 + tx) * 64 + sA * 16];
      bf[mi] = *(const l2*)&Bs[p][(wn * 64 + mi * 16 + tx) * 64 + sA * 16];
    }
    #pragma unroll
    for (int mi = 0; mi < 4; mi++)
      #pragma unroll
      for (int ni = 0; ni < 4; ni++)
        acc[mi][ni] = __builtin_amdgcn_mfma_f32_16x16x32_fp8_fp8(af[mi].x, bf[ni].x, acc[mi][ni], 0, 0, 0);
    #pragma unroll
    for (int mi = 0; mi < 4; mi++)
      #pragma unroll
      for (int ni = 0; ni < 4; ni++)
        acc[mi][ni] = __builtin_amdgcn_mfma_f32_16x16x32_fp8_fp8(af[mi].y, bf[ni].y, acc[mi][ni], 0, 0, 0);
    p ^= 1;
  }

  // epilogue: s += 2^(cubic(acc)) per class (poly pre-scaled for acc=256*cos)
  float4 cp[4];
  #pragma unroll
  for (int ni = 0; ni < 4; ni++) cp[ni] = cparams[c0 + wn * 64 + ni * 16 + tx];

  #pragma unroll
  for (int mi = 0; mi < 4; mi++) {
    #pragma unroll
    for (int reg = 0; reg < 4; reg++) {
      float s = 0.0f;
      #pragma unroll
      for (int ni = 0; ni < 4; ni++) {
        float cv = acc[mi][ni][reg];
        float g = fmaf(fmaf(fmaf(cp[ni].w, cv, cp[ni].z), cv, cp[ni].y), cv, cp[ni].x);
        s += exp2f(g);
      }
      #pragma unroll
      for (int o = 1; o < 16; o <<= 1) s += __shfl_xor(s, o, 64);
      if (tx == 0)
        atomicAdd(&rowsum[r0 + wm * 64 + mi * 16 + tz * 4 + reg], s);
    }
  }
}

// finalize: recompute both unit vectors from raw fp32 inputs
__global__ __launch_bounds__(64) void finalize_kernel(const float* __restrict__ params,
                                                      const float* __restrict__ weight,
                                                      const float* __restrict__ rowsum,
                                                      const int* __restrict__ labels,
                                                      const float* __restrict__ lscale,
                                                      float* __restrict__ out) {
  int b = blockIdx.x;
  int lane = threadIdx.x;
  int lab = labels[b];
  const float* pr = params + (size_t)b * (DIMD + 2) + 1;
  const float* wr = weight + (size_t)lab * (DIMD + 2) + 1;
  float nx = 0.0f, nw = 0.0f, d = 0.0f;
  #pragma unroll
  for (int j = 0; j < 8; j++) {
    float xv = pr[j * 64 + lane];
    float wv = wr[j * 64 + lane];
    nx += xv * xv; nw += wv * wv; d += xv * wv;
  }
  nx = wave_sum(nx); nw = wave_sum(nw); d = wave_sum(d);
  if (lane == 0) {
    float k1 = expf(lscale[0]);
    float acc = 0.0f;
    #pragma unroll
    for (int k = 0; k < KSAMP; k++) acc += __logf(rowsum[b * KSAMP + k]);
    float loss = acc * (1.0f / KSAMP) - k1 * d * rsqrtf(nx) * rsqrtf(nw);
    out[(size_t)b * NCLS + lab] = -loss;
  }
}

// ---------------- launch ----------------
extern "C" void kernel_launch(void* const* d_in, const int* in_sizes, int n_in,
                              void* d_out, int out_size, void* d_ws, size_t ws_size,
                              hipStream_t stream) {
  const float* params = (const float*)d_in[0];
  const float* weight = (const float*)d_in[1];
  const float* lscale = (const float*)d_in[2];
  const int*   labels = (const int*)d_in[3];
  float* out = (float*)d_out;
  char* ws = (char*)d_ws;

  unsigned char* muW8    = (unsigned char*)(ws);                    // 8192*512 = 4,194,304
  unsigned char* Sb8     = (unsigned char*)(ws + 4194304);          // 5120*512 = 2,621,440
  float4*        cparams = (float4*)(ws + 6815744);                 // 8192*16  =   131,072
  float*         rowsum  = (float*)(ws + 6946816);                  // 5120*4   =    20,480

  hipLaunchKernelGGL(prep_sample, dim3(2048 + BATCH * KSAMP / 4), dim3(256), 0, stream,
                     weight, params, lscale, muW8, cparams, rowsum, (float4*)out, Sb8);
  hipLaunchKernelGGL(gemm_lse, dim3((NCLS / 128) * (BATCH * KSAMP / 128)), dim3(256), 0, stream,
                     Sb8, muW8, cparams, rowsum);
  hipLaunchKernelGGL(finalize_kernel, dim3(BATCH), dim3(64), 0, stream,
                     params, weight, rowsum, labels, lscale, out);
}